// Round 10
// baseline (950.926 us; speedup 1.0000x reference)
//
#include <hip/hip_runtime.h>
#include <stdint.h>

// 2-layer LSTM, B=64, T=1024, D=512, H=32, fp32 in/out.
// Phase 1: xg0 = x @ Wih0^T + b0  (fp32 tiled GEMM)
// Phase 2: fused 2-layer scan, ONE WAVE per batch, zero barriers/LDS/DS-ops.
//   KEY (R9 model): VOP3P f16 dot2 issues at ~quarter rate on gfx950; fp32
//   v_fma_f32 is full rate (2cy). So dots use f32 FMA chains with f32 weights
//   in VGPRs and f32 h-state broadcast via v_readlane (wave-uniform SGPRs).
//   Cross-half gate exchange via v_permlane32_swap (order-proof XOR form).

#define TT 1024
#define BB 64
#define DD 512
#define HH 32
#define GG 128  // 4*H

typedef int int2v __attribute__((ext_vector_type(2)));

__device__ __forceinline__ float fast_rcp(float x) { return __builtin_amdgcn_rcpf(x); }
__device__ __forceinline__ float sigm(float s) { return fast_rcp(1.f + __expf(-s)); }
__device__ __forceinline__ float fast_tanh(float x) {
  return fmaf(2.f, fast_rcp(1.f + __expf(-2.f * x)), -1.f);
}
__device__ __forceinline__ float act_sel(float s, bool ist) {
  float z = ist ? s + s : s;
  float r = fast_rcp(1.f + __expf(-z));
  return ist ? fmaf(2.f, r, -1.f) : r;
}

// xor-32 partner, pure VALU; order-proof XOR extraction (verified R6).
__device__ __forceinline__ float partner32(float x) {
  int xi = __builtin_bit_cast(int, x);
#if __has_builtin(__builtin_amdgcn_permlane32_swap)
  int2v r = __builtin_amdgcn_permlane32_swap(xi, xi, false, false);
  return __builtin_bit_cast(float, r.x ^ r.y ^ xi);
#else
  int a = xi, b = xi;
  asm("v_permlane32_swap_b32 %0, %1" : "+v"(a), "+v"(b));
  return __builtin_bit_cast(float, a ^ b ^ xi);
#endif
}

__device__ __forceinline__ float rdlane(float v, int lane) {
  return __builtin_bit_cast(float,
      __builtin_amdgcn_readlane(__builtin_bit_cast(int, v), lane));
}

// ---------------- Phase 1: xg GEMM (unchanged, proven) ----------------
__global__ __launch_bounds__(256) void xg_gemm(const float* __restrict__ x,
                                               const float* __restrict__ W,
                                               const float* __restrict__ bih,
                                               const float* __restrict__ bhh,
                                               float* __restrict__ outp) {
  __shared__ float xs[16][68];
  __shared__ float ws[16][128];
  const int tid = threadIdx.x;
  const int m0 = blockIdx.x * 64;
  const int tr = tid >> 5;
  const int tc = tid & 31;
  const int tm = tr * 8;
  const int tn = tc * 4;
  const int sxm = tid >> 2;
  const int sxk = (tid & 3) * 4;
  const int swg = tid >> 1;
  const int swk = (tid & 1) * 8;

  float acc[8][4];
#pragma unroll
  for (int i = 0; i < 8; ++i)
#pragma unroll
    for (int j = 0; j < 4; ++j) acc[i][j] = 0.f;

  for (int k0 = 0; k0 < DD; k0 += 16) {
    const float4 xv = *(const float4*)(x + (size_t)(m0 + sxm) * DD + k0 + sxk);
    xs[sxk + 0][sxm] = xv.x;
    xs[sxk + 1][sxm] = xv.y;
    xs[sxk + 2][sxm] = xv.z;
    xs[sxk + 3][sxm] = xv.w;
    const float4 wv0 = *(const float4*)(W + (size_t)swg * DD + k0 + swk);
    const float4 wv1 = *(const float4*)(W + (size_t)swg * DD + k0 + swk + 4);
    ws[swk + 0][swg] = wv0.x;
    ws[swk + 1][swg] = wv0.y;
    ws[swk + 2][swg] = wv0.z;
    ws[swk + 3][swg] = wv0.w;
    ws[swk + 4][swg] = wv1.x;
    ws[swk + 5][swg] = wv1.y;
    ws[swk + 6][swg] = wv1.z;
    ws[swk + 7][swg] = wv1.w;
    __syncthreads();
#pragma unroll
    for (int k = 0; k < 16; ++k) {
      const float4 a0 = *(const float4*)&xs[k][tm];
      const float4 a1 = *(const float4*)&xs[k][tm + 4];
      const float4 wv = *(const float4*)&ws[k][tn];
      const float xr[8] = {a0.x, a0.y, a0.z, a0.w, a1.x, a1.y, a1.z, a1.w};
      const float wr[4] = {wv.x, wv.y, wv.z, wv.w};
#pragma unroll
      for (int i = 0; i < 8; ++i)
#pragma unroll
        for (int j = 0; j < 4; ++j) acc[i][j] = fmaf(xr[i], wr[j], acc[i][j]);
    }
    __syncthreads();
  }
  const float4 bi = *(const float4*)(bih + tn);
  const float4 bh = *(const float4*)(bhh + tn);
  const float bs[4] = {bi.x + bh.x, bi.y + bh.y, bi.z + bh.z, bi.w + bh.w};
#pragma unroll
  for (int i = 0; i < 8; ++i) {
    float4 o;
    o.x = acc[i][0] + bs[0];
    o.y = acc[i][1] + bs[1];
    o.z = acc[i][2] + bs[2];
    o.w = acc[i][3] + bs[3];
    *(float4*)(outp + (size_t)(m0 + tm + i) * GG + tn) = o;
  }
}

// ---------------- Phase 2: single-wave-per-batch scan, f32 FMA dots ---------
// Lane l: j=l&31, hi=l>>5. gA=j+64*hi (i/g gate), gB=gA+32 (f/o gate).
// h-state: f32, wave-uniform via 32x v_readlane (lanes 0..31 hold h[0..31]).
// Layer1 lags layer0 by 1 step (both dot phases read pre-update h states).
__global__ __launch_bounds__(64, 1) void lstm_scan(const float* __restrict__ xg,
                                                   const float* __restrict__ Whh0,
                                                   const float* __restrict__ Wih1,
                                                   const float* __restrict__ Whh1,
                                                   const float* __restrict__ bih1,
                                                   const float* __restrict__ bhh1,
                                                   float* __restrict__ out) {
  const int l = threadIdx.x;
  const int j = l & 31;
  const int hi = l >> 5;
  const int b = blockIdx.x;
  const int gA = j + 64 * hi;
  const int gB = gA + 32;

  // f32 weights in VGPRs (192 regs)
  float w0A[32], w0B[32], wiA[32], wiB[32], whA[32], whB[32];
#pragma unroll
  for (int q = 0; q < 8; ++q) {
    float4 a = *(const float4*)(Whh0 + (size_t)gA * HH + q * 4);
    float4 c = *(const float4*)(Whh0 + (size_t)gB * HH + q * 4);
    w0A[4 * q + 0] = a.x; w0A[4 * q + 1] = a.y; w0A[4 * q + 2] = a.z; w0A[4 * q + 3] = a.w;
    w0B[4 * q + 0] = c.x; w0B[4 * q + 1] = c.y; w0B[4 * q + 2] = c.z; w0B[4 * q + 3] = c.w;
    float4 d = *(const float4*)(Wih1 + (size_t)gA * HH + q * 4);
    float4 e = *(const float4*)(Wih1 + (size_t)gB * HH + q * 4);
    wiA[4 * q + 0] = d.x; wiA[4 * q + 1] = d.y; wiA[4 * q + 2] = d.z; wiA[4 * q + 3] = d.w;
    wiB[4 * q + 0] = e.x; wiB[4 * q + 1] = e.y; wiB[4 * q + 2] = e.z; wiB[4 * q + 3] = e.w;
    float4 f = *(const float4*)(Whh1 + (size_t)gA * HH + q * 4);
    float4 g = *(const float4*)(Whh1 + (size_t)gB * HH + q * 4);
    whA[4 * q + 0] = f.x; whA[4 * q + 1] = f.y; whA[4 * q + 2] = f.z; whA[4 * q + 3] = f.w;
    whB[4 * q + 0] = g.x; whB[4 * q + 1] = g.y; whB[4 * q + 2] = g.z; whB[4 * q + 3] = g.w;
  }
  const float b1A = bih1[gA] + bhh1[gA];
  const float b1B = bih1[gB] + bhh1[gB];

  float h0s[32], h1s[32];  // wave-uniform f32 h state
#pragma unroll
  for (int k = 0; k < 32; ++k) { h0s[k] = 0.f; h1s[k] = 0.f; }
  float c0 = 0.f, c1 = 0.f;

  const float* xgp = xg + (size_t)b * TT * GG;
  float* outp = out + (size_t)b * TT * HH;

  float xA[4], xB[4];
#pragma unroll
  for (int u = 0; u < 4; ++u) {
    xA[u] = xgp[u * GG + gA];
    xB[u] = xgp[u * GG + gB];
  }

  for (int tb = 0; tb < TT; tb += 4) {
#pragma unroll
    for (int u = 0; u < 4; ++u) {
      const int t = tb + u;
      const int tp = (t + 4 < TT) ? (t + 4) : (TT - 1);
      // ---- layer0 dots (h0s = h0[t-1]) : 4 chains per gate ----
      float a0 = xA[u], a1 = 0.f, a2 = 0.f, a3 = 0.f;
      float e0 = xB[u], e1 = 0.f, e2 = 0.f, e3 = 0.f;
      xA[u] = xgp[(size_t)tp * GG + gA];
      xB[u] = xgp[(size_t)tp * GG + gB];
#pragma unroll
      for (int k = 0; k < 32; k += 4) {
        a0 = fmaf(w0A[k + 0], h0s[k + 0], a0);
        a1 = fmaf(w0A[k + 1], h0s[k + 1], a1);
        a2 = fmaf(w0A[k + 2], h0s[k + 2], a2);
        a3 = fmaf(w0A[k + 3], h0s[k + 3], a3);
        e0 = fmaf(w0B[k + 0], h0s[k + 0], e0);
        e1 = fmaf(w0B[k + 1], h0s[k + 1], e1);
        e2 = fmaf(w0B[k + 2], h0s[k + 2], e2);
        e3 = fmaf(w0B[k + 3], h0s[k + 3], e3);
      }
      const float sA0 = (a0 + a1) + (a2 + a3);
      const float sB0 = (e0 + e1) + (e2 + e3);
      // ---- layer1 dots for step t-1 (h0s=h0[t-1], h1s=h1[t-2]) ----
      float p0 = b1A, p1 = 0.f, p2 = 0.f, p3 = 0.f;
      float q0 = b1B, q1 = 0.f, q2 = 0.f, q3 = 0.f;
#pragma unroll
      for (int k = 0; k < 32; k += 4) {
        p0 = fmaf(wiA[k + 0], h0s[k + 0], p0);
        p1 = fmaf(wiA[k + 1], h0s[k + 1], p1);
        p2 = fmaf(wiA[k + 2], h0s[k + 2], p2);
        p3 = fmaf(wiA[k + 3], h0s[k + 3], p3);
        q0 = fmaf(wiB[k + 0], h0s[k + 0], q0);
        q1 = fmaf(wiB[k + 1], h0s[k + 1], q1);
        q2 = fmaf(wiB[k + 2], h0s[k + 2], q2);
        q3 = fmaf(wiB[k + 3], h0s[k + 3], q3);
        p0 = fmaf(whA[k + 0], h1s[k + 0], p0);
        p1 = fmaf(whA[k + 1], h1s[k + 1], p1);
        p2 = fmaf(whA[k + 2], h1s[k + 2], p2);
        p3 = fmaf(whA[k + 3], h1s[k + 3], p3);
        q0 = fmaf(whB[k + 0], h1s[k + 0], q0);
        q1 = fmaf(whB[k + 1], h1s[k + 1], q1);
        q2 = fmaf(whB[k + 2], h1s[k + 2], q2);
        q3 = fmaf(whB[k + 3], h1s[k + 3], q3);
      }
      const float sA1 = (p0 + p1) + (p2 + p3);
      const float sB1 = (q0 + q1) + (q2 + q3);
      // ---- layer0 combine -> h0[t] ----
      {
        float aA = act_sel(sA0, hi != 0);  // i (hi=0) / g (hi=1)
        float aB = sigm(sB0);              // f (hi=0) / o (hi=1)
        float pAx = partner32(aA);
        float pBx = partner32(aB);
        float gi = hi ? pAx : aA;
        float gf = hi ? pBx : aB;
        float gg = hi ? aA : pAx;
        float go = hi ? aB : pBx;
        c0 = fmaf(gf, c0, gi * gg);
        float h = go * fast_tanh(c0);
#pragma unroll
        for (int m = 0; m < 32; ++m) h0s[m] = rdlane(h, m);
      }
      // ---- layer1 combine for step t-1 ----
      if (t > 0) {
        float aA = act_sel(sA1, hi != 0);
        float aB = sigm(sB1);
        float pAx = partner32(aA);
        float pBx = partner32(aB);
        float gi = hi ? pAx : aA;
        float gf = hi ? pBx : aB;
        float gg = hi ? aA : pAx;
        float go = hi ? aB : pBx;
        c1 = fmaf(gf, c1, gi * gg);
        float h = go * fast_tanh(c1);
        if (!hi) outp[(size_t)(t - 1) * HH + j] = h;
#pragma unroll
        for (int m = 0; m < 32; ++m) h1s[m] = rdlane(h, m);
      }
    }
  }
  // ---- final layer1 step (t = TT-1): h0s=h0[TT-1], h1s=h1[TT-2] ----
  {
    float p0 = b1A, p1 = 0.f, p2 = 0.f, p3 = 0.f;
    float q0 = b1B, q1 = 0.f, q2 = 0.f, q3 = 0.f;
#pragma unroll
    for (int k = 0; k < 32; k += 4) {
      p0 = fmaf(wiA[k + 0], h0s[k + 0], p0);
      p1 = fmaf(wiA[k + 1], h0s[k + 1], p1);
      p2 = fmaf(wiA[k + 2], h0s[k + 2], p2);
      p3 = fmaf(wiA[k + 3], h0s[k + 3], p3);
      q0 = fmaf(wiB[k + 0], h0s[k + 0], q0);
      q1 = fmaf(wiB[k + 1], h0s[k + 1], q1);
      q2 = fmaf(wiB[k + 2], h0s[k + 2], q2);
      q3 = fmaf(wiB[k + 3], h0s[k + 3], q3);
      p0 = fmaf(whA[k + 0], h1s[k + 0], p0);
      p1 = fmaf(whA[k + 1], h1s[k + 1], p1);
      p2 = fmaf(whA[k + 2], h1s[k + 2], p2);
      p3 = fmaf(whA[k + 3], h1s[k + 3], p3);
      q0 = fmaf(whB[k + 0], h1s[k + 0], q0);
      q1 = fmaf(whB[k + 1], h1s[k + 1], q1);
      q2 = fmaf(whB[k + 2], h1s[k + 2], q2);
      q3 = fmaf(whB[k + 3], h1s[k + 3], q3);
    }
    const float sA1 = (p0 + p1) + (p2 + p3);
    const float sB1 = (q0 + q1) + (q2 + q3);
    float aA = act_sel(sA1, hi != 0);
    float aB = sigm(sB1);
    float pAx = partner32(aA);
    float pBx = partner32(aB);
    float gi = hi ? pAx : aA;
    float gf = hi ? pBx : aB;
    float gg = hi ? aA : pAx;
    float go = hi ? aB : pBx;
    c1 = fmaf(gf, c1, gi * gg);
    float h = go * fast_tanh(c1);
    if (!hi) outp[(size_t)(TT - 1) * HH + j] = h;
  }
}

extern "C" void kernel_launch(void* const* d_in, const int* in_sizes, int n_in,
                              void* d_out, int out_size, void* d_ws, size_t ws_size,
                              hipStream_t stream) {
  const float* x = (const float*)d_in[0];
  const float* Wih0 = (const float*)d_in[1];
  const float* Whh0 = (const float*)d_in[2];
  const float* bih0 = (const float*)d_in[3];
  const float* bhh0 = (const float*)d_in[4];
  const float* Wih1 = (const float*)d_in[5];
  const float* Whh1 = (const float*)d_in[6];
  const float* bih1 = (const float*)d_in[7];
  const float* bhh1 = (const float*)d_in[8];
  float* out = (float*)d_out;
  float* xg = (float*)d_ws;  // B*T*4H*4 = 33.5 MB scratch

  xg_gemm<<<dim3((BB * TT) / 64), dim3(256), 0, stream>>>(x, Wih0, bih0, bhh0, xg);
  lstm_scan<<<dim3(BB), dim3(64), 0, stream>>>(xg, Whh0, Wih1, Whh1, bih1, bhh1, out);
}

// Round 11
// 783.120 us; speedup vs baseline: 1.2143x; 1.2143x over previous
//
#include <hip/hip_runtime.h>
#include <stdint.h>

// 2-layer LSTM, B=64, T=1024, D=512, H=32, fp32 in/out.
// Phase 1: xg0 = x @ Wih0^T + b0  (fp32 tiled GEMM)
// Phase 2: fused 2-layer scan, ONE WAVE per batch, zero barriers/LDS/DS-ops.
//   R9 cycle model (validated R6/R7/R8/R9): VOP3P f16 ops ~8cy, v_fma_f32 2cy.
//   So dots use f32 FMA chains with f32 weights in VGPRs.
//   R10 lesson: loop-invariant weight loads get REMATERIALIZED by LLVM instead
//   of staying resident (VGPR=128, loads re-issued every step). Fix: pin each
//   weight with asm volatile("" : "+v"(w)) -> opaque def, must stay in VGPR.

#define TT 1024
#define BB 64
#define DD 512
#define HH 32
#define GG 128  // 4*H

typedef int int2v __attribute__((ext_vector_type(2)));

__device__ __forceinline__ float fast_rcp(float x) { return __builtin_amdgcn_rcpf(x); }
__device__ __forceinline__ float sigm(float s) { return fast_rcp(1.f + __expf(-s)); }
__device__ __forceinline__ float fast_tanh(float x) {
  return fmaf(2.f, fast_rcp(1.f + __expf(-2.f * x)), -1.f);
}
__device__ __forceinline__ float act_sel(float s, bool ist) {
  float z = ist ? s + s : s;
  float r = fast_rcp(1.f + __expf(-z));
  return ist ? fmaf(2.f, r, -1.f) : r;
}

// xor-32 partner, pure VALU; order-proof XOR extraction (verified R6).
__device__ __forceinline__ float partner32(float x) {
  int xi = __builtin_bit_cast(int, x);
#if __has_builtin(__builtin_amdgcn_permlane32_swap)
  int2v r = __builtin_amdgcn_permlane32_swap(xi, xi, false, false);
  return __builtin_bit_cast(float, r.x ^ r.y ^ xi);
#else
  int a = xi, b = xi;
  asm("v_permlane32_swap_b32 %0, %1" : "+v"(a), "+v"(b));
  return __builtin_bit_cast(float, a ^ b ^ xi);
#endif
}

__device__ __forceinline__ float rdlane(float v, int lane) {
  return __builtin_bit_cast(float,
      __builtin_amdgcn_readlane(__builtin_bit_cast(int, v), lane));
}

// ---------------- Phase 1: xg GEMM (unchanged, proven) ----------------
__global__ __launch_bounds__(256) void xg_gemm(const float* __restrict__ x,
                                               const float* __restrict__ W,
                                               const float* __restrict__ bih,
                                               const float* __restrict__ bhh,
                                               float* __restrict__ outp) {
  __shared__ float xs[16][68];
  __shared__ float ws[16][128];
  const int tid = threadIdx.x;
  const int m0 = blockIdx.x * 64;
  const int tr = tid >> 5;
  const int tc = tid & 31;
  const int tm = tr * 8;
  const int tn = tc * 4;
  const int sxm = tid >> 2;
  const int sxk = (tid & 3) * 4;
  const int swg = tid >> 1;
  const int swk = (tid & 1) * 8;

  float acc[8][4];
#pragma unroll
  for (int i = 0; i < 8; ++i)
#pragma unroll
    for (int j = 0; j < 4; ++j) acc[i][j] = 0.f;

  for (int k0 = 0; k0 < DD; k0 += 16) {
    const float4 xv = *(const float4*)(x + (size_t)(m0 + sxm) * DD + k0 + sxk);
    xs[sxk + 0][sxm] = xv.x;
    xs[sxk + 1][sxm] = xv.y;
    xs[sxk + 2][sxm] = xv.z;
    xs[sxk + 3][sxm] = xv.w;
    const float4 wv0 = *(const float4*)(W + (size_t)swg * DD + k0 + swk);
    const float4 wv1 = *(const float4*)(W + (size_t)swg * DD + k0 + swk + 4);
    ws[swk + 0][swg] = wv0.x;
    ws[swk + 1][swg] = wv0.y;
    ws[swk + 2][swg] = wv0.z;
    ws[swk + 3][swg] = wv0.w;
    ws[swk + 4][swg] = wv1.x;
    ws[swk + 5][swg] = wv1.y;
    ws[swk + 6][swg] = wv1.z;
    ws[swk + 7][swg] = wv1.w;
    __syncthreads();
#pragma unroll
    for (int k = 0; k < 16; ++k) {
      const float4 a0 = *(const float4*)&xs[k][tm];
      const float4 a1 = *(const float4*)&xs[k][tm + 4];
      const float4 wv = *(const float4*)&ws[k][tn];
      const float xr[8] = {a0.x, a0.y, a0.z, a0.w, a1.x, a1.y, a1.z, a1.w};
      const float wr[4] = {wv.x, wv.y, wv.z, wv.w};
#pragma unroll
      for (int i = 0; i < 8; ++i)
#pragma unroll
        for (int j = 0; j < 4; ++j) acc[i][j] = fmaf(xr[i], wr[j], acc[i][j]);
    }
    __syncthreads();
  }
  const float4 bi = *(const float4*)(bih + tn);
  const float4 bh = *(const float4*)(bhh + tn);
  const float bs[4] = {bi.x + bh.x, bi.y + bh.y, bi.z + bh.z, bi.w + bh.w};
#pragma unroll
  for (int i = 0; i < 8; ++i) {
    float4 o;
    o.x = acc[i][0] + bs[0];
    o.y = acc[i][1] + bs[1];
    o.z = acc[i][2] + bs[2];
    o.w = acc[i][3] + bs[3];
    *(float4*)(outp + (size_t)(m0 + tm + i) * GG + tn) = o;
  }
}

// ---------------- Phase 2: single-wave-per-batch scan, f32 FMA dots ---------
// Lane l: j=l&31, hi=l>>5. gA=j+64*hi (i/g gate), gB=gA+32 (f/o gate).
// h-state: f32, wave-uniform via 32x v_readlane (SGPRs).
// Layer1 lags layer0 by 1 step (both dot phases read pre-update h states).
__global__ __launch_bounds__(64, 1) void lstm_scan(const float* __restrict__ xg,
                                                   const float* __restrict__ Whh0,
                                                   const float* __restrict__ Wih1,
                                                   const float* __restrict__ Whh1,
                                                   const float* __restrict__ bih1,
                                                   const float* __restrict__ bhh1,
                                                   float* __restrict__ out) {
  const int l = threadIdx.x;
  const int j = l & 31;
  const int hi = l >> 5;
  const int b = blockIdx.x;
  const int gA = j + 64 * hi;
  const int gB = gA + 32;

  // f32 weights in VGPRs (192 regs), PINNED against rematerialization.
  float w0A[32], w0B[32], wiA[32], wiB[32], whA[32], whB[32];
#pragma unroll
  for (int q = 0; q < 8; ++q) {
    float4 a = *(const float4*)(Whh0 + (size_t)gA * HH + q * 4);
    float4 c = *(const float4*)(Whh0 + (size_t)gB * HH + q * 4);
    w0A[4 * q + 0] = a.x; w0A[4 * q + 1] = a.y; w0A[4 * q + 2] = a.z; w0A[4 * q + 3] = a.w;
    w0B[4 * q + 0] = c.x; w0B[4 * q + 1] = c.y; w0B[4 * q + 2] = c.z; w0B[4 * q + 3] = c.w;
    float4 d = *(const float4*)(Wih1 + (size_t)gA * HH + q * 4);
    float4 e = *(const float4*)(Wih1 + (size_t)gB * HH + q * 4);
    wiA[4 * q + 0] = d.x; wiA[4 * q + 1] = d.y; wiA[4 * q + 2] = d.z; wiA[4 * q + 3] = d.w;
    wiB[4 * q + 0] = e.x; wiB[4 * q + 1] = e.y; wiB[4 * q + 2] = e.z; wiB[4 * q + 3] = e.w;
    float4 f = *(const float4*)(Whh1 + (size_t)gA * HH + q * 4);
    float4 g = *(const float4*)(Whh1 + (size_t)gB * HH + q * 4);
    whA[4 * q + 0] = f.x; whA[4 * q + 1] = f.y; whA[4 * q + 2] = f.z; whA[4 * q + 3] = f.w;
    whB[4 * q + 0] = g.x; whB[4 * q + 1] = g.y; whB[4 * q + 2] = g.z; whB[4 * q + 3] = g.w;
  }
  // Pin: opaque def -> compiler cannot re-load from memory inside the loop.
#pragma unroll
  for (int k = 0; k < 32; ++k) {
    asm volatile("" : "+v"(w0A[k]));
    asm volatile("" : "+v"(w0B[k]));
    asm volatile("" : "+v"(wiA[k]));
    asm volatile("" : "+v"(wiB[k]));
    asm volatile("" : "+v"(whA[k]));
    asm volatile("" : "+v"(whB[k]));
  }
  const float b1A = bih1[gA] + bhh1[gA];
  const float b1B = bih1[gB] + bhh1[gB];

  float h0s[32], h1s[32];  // wave-uniform f32 h state (SGPRs)
#pragma unroll
  for (int k = 0; k < 32; ++k) { h0s[k] = 0.f; h1s[k] = 0.f; }
  float c0 = 0.f, c1 = 0.f;

  const float* xgp = xg + (size_t)b * TT * GG;
  float* outp = out + (size_t)b * TT * HH;

  float xA[4], xB[4];
#pragma unroll
  for (int u = 0; u < 4; ++u) {
    xA[u] = xgp[u * GG + gA];
    xB[u] = xgp[u * GG + gB];
  }

  for (int tb = 0; tb < TT; tb += 4) {
#pragma unroll
    for (int u = 0; u < 4; ++u) {
      const int t = tb + u;
      const int tp = (t + 4 < TT) ? (t + 4) : (TT - 1);
      // ---- layer0 dots (h0s = h0[t-1]) : 4 chains per gate ----
      float a0 = xA[u], a1 = 0.f, a2 = 0.f, a3 = 0.f;
      float e0 = xB[u], e1 = 0.f, e2 = 0.f, e3 = 0.f;
      xA[u] = xgp[(size_t)tp * GG + gA];
      xB[u] = xgp[(size_t)tp * GG + gB];
#pragma unroll
      for (int k = 0; k < 32; k += 4) {
        a0 = fmaf(w0A[k + 0], h0s[k + 0], a0);
        a1 = fmaf(w0A[k + 1], h0s[k + 1], a1);
        a2 = fmaf(w0A[k + 2], h0s[k + 2], a2);
        a3 = fmaf(w0A[k + 3], h0s[k + 3], a3);
        e0 = fmaf(w0B[k + 0], h0s[k + 0], e0);
        e1 = fmaf(w0B[k + 1], h0s[k + 1], e1);
        e2 = fmaf(w0B[k + 2], h0s[k + 2], e2);
        e3 = fmaf(w0B[k + 3], h0s[k + 3], e3);
      }
      const float sA0 = (a0 + a1) + (a2 + a3);
      const float sB0 = (e0 + e1) + (e2 + e3);
      // ---- layer1 dots for step t-1 (h0s=h0[t-1], h1s=h1[t-2]) ----
      float p0 = b1A, p1 = 0.f, p2 = 0.f, p3 = 0.f;
      float q0 = b1B, q1 = 0.f, q2 = 0.f, q3 = 0.f;
#pragma unroll
      for (int k = 0; k < 32; k += 4) {
        p0 = fmaf(wiA[k + 0], h0s[k + 0], p0);
        p1 = fmaf(wiA[k + 1], h0s[k + 1], p1);
        p2 = fmaf(wiA[k + 2], h0s[k + 2], p2);
        p3 = fmaf(wiA[k + 3], h0s[k + 3], p3);
        q0 = fmaf(wiB[k + 0], h0s[k + 0], q0);
        q1 = fmaf(wiB[k + 1], h0s[k + 1], q1);
        q2 = fmaf(wiB[k + 2], h0s[k + 2], q2);
        q3 = fmaf(wiB[k + 3], h0s[k + 3], q3);
        p0 = fmaf(whA[k + 0], h1s[k + 0], p0);
        p1 = fmaf(whA[k + 1], h1s[k + 1], p1);
        p2 = fmaf(whA[k + 2], h1s[k + 2], p2);
        p3 = fmaf(whA[k + 3], h1s[k + 3], p3);
        q0 = fmaf(whB[k + 0], h1s[k + 0], q0);
        q1 = fmaf(whB[k + 1], h1s[k + 1], q1);
        q2 = fmaf(whB[k + 2], h1s[k + 2], q2);
        q3 = fmaf(whB[k + 3], h1s[k + 3], q3);
      }
      const float sA1 = (p0 + p1) + (p2 + p3);
      const float sB1 = (q0 + q1) + (q2 + q3);
      // ---- layer0 combine -> h0[t] ----
      {
        float aA = act_sel(sA0, hi != 0);  // i (hi=0) / g (hi=1)
        float aB = sigm(sB0);              // f (hi=0) / o (hi=1)
        float pAx = partner32(aA);
        float pBx = partner32(aB);
        float gi = hi ? pAx : aA;
        float gf = hi ? pBx : aB;
        float gg = hi ? aA : pAx;
        float go = hi ? aB : pBx;
        c0 = fmaf(gf, c0, gi * gg);
        float h = go * fast_tanh(c0);
#pragma unroll
        for (int m = 0; m < 32; ++m) h0s[m] = rdlane(h, m);
      }
      // ---- layer1 combine for step t-1 ----
      if (t > 0) {
        float aA = act_sel(sA1, hi != 0);
        float aB = sigm(sB1);
        float pAx = partner32(aA);
        float pBx = partner32(aB);
        float gi = hi ? pAx : aA;
        float gf = hi ? pBx : aB;
        float gg = hi ? aA : pAx;
        float go = hi ? aB : pBx;
        c1 = fmaf(gf, c1, gi * gg);
        float h = go * fast_tanh(c1);
        if (!hi) outp[(size_t)(t - 1) * HH + j] = h;
#pragma unroll
        for (int m = 0; m < 32; ++m) h1s[m] = rdlane(h, m);
      }
    }
  }
  // ---- final layer1 step (t = TT-1): h0s=h0[TT-1], h1s=h1[TT-2] ----
  {
    float p0 = b1A, p1 = 0.f, p2 = 0.f, p3 = 0.f;
    float q0 = b1B, q1 = 0.f, q2 = 0.f, q3 = 0.f;
#pragma unroll
    for (int k = 0; k < 32; k += 4) {
      p0 = fmaf(wiA[k + 0], h0s[k + 0], p0);
      p1 = fmaf(wiA[k + 1], h0s[k + 1], p1);
      p2 = fmaf(wiA[k + 2], h0s[k + 2], p2);
      p3 = fmaf(wiA[k + 3], h0s[k + 3], p3);
      q0 = fmaf(wiB[k + 0], h0s[k + 0], q0);
      q1 = fmaf(wiB[k + 1], h0s[k + 1], q1);
      q2 = fmaf(wiB[k + 2], h0s[k + 2], q2);
      q3 = fmaf(wiB[k + 3], h0s[k + 3], q3);
      p0 = fmaf(whA[k + 0], h1s[k + 0], p0);
      p1 = fmaf(whA[k + 1], h1s[k + 1], p1);
      p2 = fmaf(whA[k + 2], h1s[k + 2], p2);
      p3 = fmaf(whA[k + 3], h1s[k + 3], p3);
      q0 = fmaf(whB[k + 0], h1s[k + 0], q0);
      q1 = fmaf(whB[k + 1], h1s[k + 1], q1);
      q2 = fmaf(whB[k + 2], h1s[k + 2], q2);
      q3 = fmaf(whB[k + 3], h1s[k + 3], q3);
    }
    const float sA1 = (p0 + p1) + (p2 + p3);
    const float sB1 = (q0 + q1) + (q2 + q3);
    float aA = act_sel(sA1, hi != 0);
    float aB = sigm(sB1);
    float pAx = partner32(aA);
    float pBx = partner32(aB);
    float gi = hi ? pAx : aA;
    float gf = hi ? pBx : aB;
    float gg = hi ? aA : pAx;
    float go = hi ? aB : pBx;
    c1 = fmaf(gf, c1, gi * gg);
    float h = go * fast_tanh(c1);
    if (!hi) outp[(size_t)(TT - 1) * HH + j] = h;
  }
}

extern "C" void kernel_launch(void* const* d_in, const int* in_sizes, int n_in,
                              void* d_out, int out_size, void* d_ws, size_t ws_size,
                              hipStream_t stream) {
  const float* x = (const float*)d_in[0];
  const float* Wih0 = (const float*)d_in[1];
  const float* Whh0 = (const float*)d_in[2];
  const float* bih0 = (const float*)d_in[3];
  const float* bhh0 = (const float*)d_in[4];
  const float* Wih1 = (const float*)d_in[5];
  const float* Whh1 = (const float*)d_in[6];
  const float* bih1 = (const float*)d_in[7];
  const float* bhh1 = (const float*)d_in[8];
  float* out = (float*)d_out;
  float* xg = (float*)d_ws;  // B*T*4H*4 = 33.5 MB scratch

  xg_gemm<<<dim3((BB * TT) / 64), dim3(256), 0, stream>>>(x, Wih0, bih0, bhh0, xg);
  lstm_scan<<<dim3(BB), dim3(64), 0, stream>>>(xg, Whh0, Wih1, Whh1, bih1, bhh1, out);
}

// Round 12
// 782.625 us; speedup vs baseline: 1.2150x; 1.0006x over previous
//
#include <hip/hip_runtime.h>
#include <stdint.h>

// 2-layer LSTM, B=64, T=1024, D=512, H=32, fp32 in/out.
// Phase 1: xg0 = x @ Wih0^T + b0  (fp32 tiled GEMM)
// Phase 2: fused 2-layer scan, ONE WAVE per batch, zero barriers/LDS/DS-ops.
//   Cycle model (validated R6-R9): VOP3P f16 dot2 ~8cy, v_fma_f32 2cy ->
//   f32 FMA chains with f32 weights resident in VGPRs.
//   R11 lesson: launch_bounds(64,1) does NOT stop the allocator from targeting
//   4 waves/EU (VGPR cap 128 -> weight spills). amdgpu_waves_per_eu(1,1)
//   forces the 512-VGPR budget so 192 weight regs actually stay resident.

#define TT 1024
#define BB 64
#define DD 512
#define HH 32
#define GG 128  // 4*H

typedef int int2v __attribute__((ext_vector_type(2)));

__device__ __forceinline__ float fast_rcp(float x) { return __builtin_amdgcn_rcpf(x); }
__device__ __forceinline__ float sigm(float s) { return fast_rcp(1.f + __expf(-s)); }
__device__ __forceinline__ float fast_tanh(float x) {
  return fmaf(2.f, fast_rcp(1.f + __expf(-2.f * x)), -1.f);
}
__device__ __forceinline__ float act_sel(float s, bool ist) {
  float z = ist ? s + s : s;
  float r = fast_rcp(1.f + __expf(-z));
  return ist ? fmaf(2.f, r, -1.f) : r;
}

// xor-32 partner, pure VALU; order-proof XOR extraction (verified R6).
__device__ __forceinline__ float partner32(float x) {
  int xi = __builtin_bit_cast(int, x);
#if __has_builtin(__builtin_amdgcn_permlane32_swap)
  int2v r = __builtin_amdgcn_permlane32_swap(xi, xi, false, false);
  return __builtin_bit_cast(float, r.x ^ r.y ^ xi);
#else
  int a = xi, b = xi;
  asm("v_permlane32_swap_b32 %0, %1" : "+v"(a), "+v"(b));
  return __builtin_bit_cast(float, a ^ b ^ xi);
#endif
}

__device__ __forceinline__ float rdlane(float v, int lane) {
  return __builtin_bit_cast(float,
      __builtin_amdgcn_readlane(__builtin_bit_cast(int, v), lane));
}

// ---------------- Phase 1: xg GEMM (unchanged, proven) ----------------
__global__ __launch_bounds__(256) void xg_gemm(const float* __restrict__ x,
                                               const float* __restrict__ W,
                                               const float* __restrict__ bih,
                                               const float* __restrict__ bhh,
                                               float* __restrict__ outp) {
  __shared__ float xs[16][68];
  __shared__ float ws[16][128];
  const int tid = threadIdx.x;
  const int m0 = blockIdx.x * 64;
  const int tr = tid >> 5;
  const int tc = tid & 31;
  const int tm = tr * 8;
  const int tn = tc * 4;
  const int sxm = tid >> 2;
  const int sxk = (tid & 3) * 4;
  const int swg = tid >> 1;
  const int swk = (tid & 1) * 8;

  float acc[8][4];
#pragma unroll
  for (int i = 0; i < 8; ++i)
#pragma unroll
    for (int j = 0; j < 4; ++j) acc[i][j] = 0.f;

  for (int k0 = 0; k0 < DD; k0 += 16) {
    const float4 xv = *(const float4*)(x + (size_t)(m0 + sxm) * DD + k0 + sxk);
    xs[sxk + 0][sxm] = xv.x;
    xs[sxk + 1][sxm] = xv.y;
    xs[sxk + 2][sxm] = xv.z;
    xs[sxk + 3][sxm] = xv.w;
    const float4 wv0 = *(const float4*)(W + (size_t)swg * DD + k0 + swk);
    const float4 wv1 = *(const float4*)(W + (size_t)swg * DD + k0 + swk + 4);
    ws[swk + 0][swg] = wv0.x;
    ws[swk + 1][swg] = wv0.y;
    ws[swk + 2][swg] = wv0.z;
    ws[swk + 3][swg] = wv0.w;
    ws[swk + 4][swg] = wv1.x;
    ws[swk + 5][swg] = wv1.y;
    ws[swk + 6][swg] = wv1.z;
    ws[swk + 7][swg] = wv1.w;
    __syncthreads();
#pragma unroll
    for (int k = 0; k < 16; ++k) {
      const float4 a0 = *(const float4*)&xs[k][tm];
      const float4 a1 = *(const float4*)&xs[k][tm + 4];
      const float4 wv = *(const float4*)&ws[k][tn];
      const float xr[8] = {a0.x, a0.y, a0.z, a0.w, a1.x, a1.y, a1.z, a1.w};
      const float wr[4] = {wv.x, wv.y, wv.z, wv.w};
#pragma unroll
      for (int i = 0; i < 8; ++i)
#pragma unroll
        for (int j = 0; j < 4; ++j) acc[i][j] = fmaf(xr[i], wr[j], acc[i][j]);
    }
    __syncthreads();
  }
  const float4 bi = *(const float4*)(bih + tn);
  const float4 bh = *(const float4*)(bhh + tn);
  const float bs[4] = {bi.x + bh.x, bi.y + bh.y, bi.z + bh.z, bi.w + bh.w};
#pragma unroll
  for (int i = 0; i < 8; ++i) {
    float4 o;
    o.x = acc[i][0] + bs[0];
    o.y = acc[i][1] + bs[1];
    o.z = acc[i][2] + bs[2];
    o.w = acc[i][3] + bs[3];
    *(float4*)(outp + (size_t)(m0 + tm + i) * GG + tn) = o;
  }
}

// ---------------- Phase 2: single-wave-per-batch scan, f32 FMA dots ---------
// Lane l: j=l&31, hi=l>>5. gA=j+64*hi (i/g gate), gB=gA+32 (f/o gate).
// h-state: f32, wave-uniform via 32x v_readlane (SGPRs).
// Layer1 lags layer0 by 1 step (both dot phases read pre-update h states).
__global__ __launch_bounds__(64)
__attribute__((amdgpu_waves_per_eu(1, 1)))
void lstm_scan(const float* __restrict__ xg,
               const float* __restrict__ Whh0,
               const float* __restrict__ Wih1,
               const float* __restrict__ Whh1,
               const float* __restrict__ bih1,
               const float* __restrict__ bhh1,
               float* __restrict__ out) {
  const int l = threadIdx.x;
  const int j = l & 31;
  const int hi = l >> 5;
  const int b = blockIdx.x;
  const int gA = j + 64 * hi;
  const int gB = gA + 32;

  // f32 weights in VGPRs (192 regs), PINNED against rematerialization.
  float w0A[32], w0B[32], wiA[32], wiB[32], whA[32], whB[32];
#pragma unroll
  for (int q = 0; q < 8; ++q) {
    float4 a = *(const float4*)(Whh0 + (size_t)gA * HH + q * 4);
    float4 c = *(const float4*)(Whh0 + (size_t)gB * HH + q * 4);
    w0A[4 * q + 0] = a.x; w0A[4 * q + 1] = a.y; w0A[4 * q + 2] = a.z; w0A[4 * q + 3] = a.w;
    w0B[4 * q + 0] = c.x; w0B[4 * q + 1] = c.y; w0B[4 * q + 2] = c.z; w0B[4 * q + 3] = c.w;
    float4 d = *(const float4*)(Wih1 + (size_t)gA * HH + q * 4);
    float4 e = *(const float4*)(Wih1 + (size_t)gB * HH + q * 4);
    wiA[4 * q + 0] = d.x; wiA[4 * q + 1] = d.y; wiA[4 * q + 2] = d.z; wiA[4 * q + 3] = d.w;
    wiB[4 * q + 0] = e.x; wiB[4 * q + 1] = e.y; wiB[4 * q + 2] = e.z; wiB[4 * q + 3] = e.w;
    float4 f = *(const float4*)(Whh1 + (size_t)gA * HH + q * 4);
    float4 g = *(const float4*)(Whh1 + (size_t)gB * HH + q * 4);
    whA[4 * q + 0] = f.x; whA[4 * q + 1] = f.y; whA[4 * q + 2] = f.z; whA[4 * q + 3] = f.w;
    whB[4 * q + 0] = g.x; whB[4 * q + 1] = g.y; whB[4 * q + 2] = g.z; whB[4 * q + 3] = g.w;
  }
  // Pin: opaque def -> compiler cannot re-load from memory inside the loop.
#pragma unroll
  for (int k = 0; k < 32; ++k) {
    asm volatile("" : "+v"(w0A[k]));
    asm volatile("" : "+v"(w0B[k]));
    asm volatile("" : "+v"(wiA[k]));
    asm volatile("" : "+v"(wiB[k]));
    asm volatile("" : "+v"(whA[k]));
    asm volatile("" : "+v"(whB[k]));
  }
  const float b1A = bih1[gA] + bhh1[gA];
  const float b1B = bih1[gB] + bhh1[gB];

  float h0s[32], h1s[32];  // wave-uniform f32 h state (SGPRs)
#pragma unroll
  for (int k = 0; k < 32; ++k) { h0s[k] = 0.f; h1s[k] = 0.f; }
  float c0 = 0.f, c1 = 0.f;

  const float* xgp = xg + (size_t)b * TT * GG;
  float* outp = out + (size_t)b * TT * HH;

  float xA[4], xB[4];
#pragma unroll
  for (int u = 0; u < 4; ++u) {
    xA[u] = xgp[u * GG + gA];
    xB[u] = xgp[u * GG + gB];
  }

  for (int tb = 0; tb < TT; tb += 4) {
#pragma unroll
    for (int u = 0; u < 4; ++u) {
      const int t = tb + u;
      const int tp = (t + 4 < TT) ? (t + 4) : (TT - 1);
      // ---- layer0 dots (h0s = h0[t-1]) : 4 chains per gate ----
      float a0 = xA[u], a1 = 0.f, a2 = 0.f, a3 = 0.f;
      float e0 = xB[u], e1 = 0.f, e2 = 0.f, e3 = 0.f;
      xA[u] = xgp[(size_t)tp * GG + gA];
      xB[u] = xgp[(size_t)tp * GG + gB];
#pragma unroll
      for (int k = 0; k < 32; k += 4) {
        a0 = fmaf(w0A[k + 0], h0s[k + 0], a0);
        a1 = fmaf(w0A[k + 1], h0s[k + 1], a1);
        a2 = fmaf(w0A[k + 2], h0s[k + 2], a2);
        a3 = fmaf(w0A[k + 3], h0s[k + 3], a3);
        e0 = fmaf(w0B[k + 0], h0s[k + 0], e0);
        e1 = fmaf(w0B[k + 1], h0s[k + 1], e1);
        e2 = fmaf(w0B[k + 2], h0s[k + 2], e2);
        e3 = fmaf(w0B[k + 3], h0s[k + 3], e3);
      }
      const float sA0 = (a0 + a1) + (a2 + a3);
      const float sB0 = (e0 + e1) + (e2 + e3);
      // ---- layer1 dots for step t-1 (h0s=h0[t-1], h1s=h1[t-2]) ----
      float p0 = b1A, p1 = 0.f, p2 = 0.f, p3 = 0.f;
      float q0 = b1B, q1 = 0.f, q2 = 0.f, q3 = 0.f;
#pragma unroll
      for (int k = 0; k < 32; k += 4) {
        p0 = fmaf(wiA[k + 0], h0s[k + 0], p0);
        p1 = fmaf(wiA[k + 1], h0s[k + 1], p1);
        p2 = fmaf(wiA[k + 2], h0s[k + 2], p2);
        p3 = fmaf(wiA[k + 3], h0s[k + 3], p3);
        q0 = fmaf(wiB[k + 0], h0s[k + 0], q0);
        q1 = fmaf(wiB[k + 1], h0s[k + 1], q1);
        q2 = fmaf(wiB[k + 2], h0s[k + 2], q2);
        q3 = fmaf(wiB[k + 3], h0s[k + 3], q3);
        p0 = fmaf(whA[k + 0], h1s[k + 0], p0);
        p1 = fmaf(whA[k + 1], h1s[k + 1], p1);
        p2 = fmaf(whA[k + 2], h1s[k + 2], p2);
        p3 = fmaf(whA[k + 3], h1s[k + 3], p3);
        q0 = fmaf(whB[k + 0], h1s[k + 0], q0);
        q1 = fmaf(whB[k + 1], h1s[k + 1], q1);
        q2 = fmaf(whB[k + 2], h1s[k + 2], q2);
        q3 = fmaf(whB[k + 3], h1s[k + 3], q3);
      }
      const float sA1 = (p0 + p1) + (p2 + p3);
      const float sB1 = (q0 + q1) + (q2 + q3);
      // ---- layer0 combine -> h0[t] ----
      {
        float aA = act_sel(sA0, hi != 0);  // i (hi=0) / g (hi=1)
        float aB = sigm(sB0);              // f (hi=0) / o (hi=1)
        float pAx = partner32(aA);
        float pBx = partner32(aB);
        float gi = hi ? pAx : aA;
        float gf = hi ? pBx : aB;
        float gg = hi ? aA : pAx;
        float go = hi ? aB : pBx;
        c0 = fmaf(gf, c0, gi * gg);
        float h = go * fast_tanh(c0);
#pragma unroll
        for (int m = 0; m < 32; ++m) h0s[m] = rdlane(h, m);
      }
      // ---- layer1 combine for step t-1 ----
      if (t > 0) {
        float aA = act_sel(sA1, hi != 0);
        float aB = sigm(sB1);
        float pAx = partner32(aA);
        float pBx = partner32(aB);
        float gi = hi ? pAx : aA;
        float gf = hi ? pBx : aB;
        float gg = hi ? aA : pAx;
        float go = hi ? aB : pBx;
        c1 = fmaf(gf, c1, gi * gg);
        float h = go * fast_tanh(c1);
        if (!hi) outp[(size_t)(t - 1) * HH + j] = h;
#pragma unroll
        for (int m = 0; m < 32; ++m) h1s[m] = rdlane(h, m);
      }
    }
  }
  // ---- final layer1 step (t = TT-1): h0s=h0[TT-1], h1s=h1[TT-2] ----
  {
    float p0 = b1A, p1 = 0.f, p2 = 0.f, p3 = 0.f;
    float q0 = b1B, q1 = 0.f, q2 = 0.f, q3 = 0.f;
#pragma unroll
    for (int k = 0; k < 32; k += 4) {
      p0 = fmaf(wiA[k + 0], h0s[k + 0], p0);
      p1 = fmaf(wiA[k + 1], h0s[k + 1], p1);
      p2 = fmaf(wiA[k + 2], h0s[k + 2], p2);
      p3 = fmaf(wiA[k + 3], h0s[k + 3], p3);
      q0 = fmaf(wiB[k + 0], h0s[k + 0], q0);
      q1 = fmaf(wiB[k + 1], h0s[k + 1], q1);
      q2 = fmaf(wiB[k + 2], h0s[k + 2], q2);
      q3 = fmaf(wiB[k + 3], h0s[k + 3], q3);
      p0 = fmaf(whA[k + 0], h1s[k + 0], p0);
      p1 = fmaf(whA[k + 1], h1s[k + 1], p1);
      p2 = fmaf(whA[k + 2], h1s[k + 2], p2);
      p3 = fmaf(whA[k + 3], h1s[k + 3], p3);
      q0 = fmaf(whB[k + 0], h1s[k + 0], q0);
      q1 = fmaf(whB[k + 1], h1s[k + 1], q1);
      q2 = fmaf(whB[k + 2], h1s[k + 2], q2);
      q3 = fmaf(whB[k + 3], h1s[k + 3], q3);
    }
    const float sA1 = (p0 + p1) + (p2 + p3);
    const float sB1 = (q0 + q1) + (q2 + q3);
    float aA = act_sel(sA1, hi != 0);
    float aB = sigm(sB1);
    float pAx = partner32(aA);
    float pBx = partner32(aB);
    float gi = hi ? pAx : aA;
    float gf = hi ? pBx : aB;
    float gg = hi ? aA : pAx;
    float go = hi ? aB : pBx;
    c1 = fmaf(gf, c1, gi * gg);
    float h = go * fast_tanh(c1);
    if (!hi) outp[(size_t)(TT - 1) * HH + j] = h;
  }
}

extern "C" void kernel_launch(void* const* d_in, const int* in_sizes, int n_in,
                              void* d_out, int out_size, void* d_ws, size_t ws_size,
                              hipStream_t stream) {
  const float* x = (const float*)d_in[0];
  const float* Wih0 = (const float*)d_in[1];
  const float* Whh0 = (const float*)d_in[2];
  const float* bih0 = (const float*)d_in[3];
  const float* bhh0 = (const float*)d_in[4];
  const float* Wih1 = (const float*)d_in[5];
  const float* Whh1 = (const float*)d_in[6];
  const float* bih1 = (const float*)d_in[7];
  const float* bhh1 = (const float*)d_in[8];
  float* out = (float*)d_out;
  float* xg = (float*)d_ws;  // B*T*4H*4 = 33.5 MB scratch

  xg_gemm<<<dim3((BB * TT) / 64), dim3(256), 0, stream>>>(x, Wih0, bih0, bhh0, xg);
  lstm_scan<<<dim3(BB), dim3(64), 0, stream>>>(xg, Whh0, Wih1, Whh1, bih1, bhh1, out);
}

// Round 13
// 573.726 us; speedup vs baseline: 1.6575x; 1.3641x over previous
//
#include <hip/hip_runtime.h>
#include <stdint.h>

// 2-layer LSTM, B=64, T=1024, D=512, H=32, fp32 in/out.
// Phase 1: xg0 = x @ Wih0^T + b0  (fp32 tiled GEMM)
// Phase 2: fused 2-layer scan (R6 structure, best at 464us): ONE WAVE per
//   batch, f16-packed weights (96 dwords/lane), v_dot2_f32_f16 dots,
//   permlane32_swap + DPP cross-lane, readlane h-broadcast to SGPRs.
//   R12 finding: even R6 spilled ~40 weight regs (VGPR=80 < 96 needed) ->
//   per-step spill-reloads. This round: pin all 96 weight dwords with opaque
//   asm (non-rematerializable) + waves_per_eu(1) so the full set stays
//   resident. Decisive A/B vs R6: isolates remat cost from dot2 issue rate.

#define TT 1024
#define BB 64
#define DD 512
#define HH 32
#define GG 128  // 4*H

typedef _Float16 h2v __attribute__((ext_vector_type(2)));
typedef __fp16 pk2 __attribute__((ext_vector_type(2)));
typedef int int2v __attribute__((ext_vector_type(2)));

__device__ __forceinline__ uint32_t pack2(float lo, float hi) {
  pk2 p = __builtin_amdgcn_cvt_pkrtz(lo, hi);
  return __builtin_bit_cast(uint32_t, p);
}
__device__ __forceinline__ float dot2(uint32_t a, uint32_t b, float acc) {
  return __builtin_amdgcn_fdot2(__builtin_bit_cast(h2v, a),
                                __builtin_bit_cast(h2v, b), acc, false);
}
__device__ __forceinline__ float fast_rcp(float x) { return __builtin_amdgcn_rcpf(x); }
__device__ __forceinline__ float sigm(float s) { return fast_rcp(1.f + __expf(-s)); }
__device__ __forceinline__ float fast_tanh(float x) {
  return fmaf(2.f, fast_rcp(1.f + __expf(-2.f * x)), -1.f);
}
__device__ __forceinline__ float act_sel(float s, bool ist) {
  float z = ist ? s + s : s;
  float r = fast_rcp(1.f + __expf(-z));
  return ist ? fmaf(2.f, r, -1.f) : r;
}

// xor-32 partner, pure VALU; order-proof XOR extraction (verified R6).
__device__ __forceinline__ float partner32(float x) {
  int xi = __builtin_bit_cast(int, x);
#if __has_builtin(__builtin_amdgcn_permlane32_swap)
  int2v r = __builtin_amdgcn_permlane32_swap(xi, xi, false, false);
  return __builtin_bit_cast(float, r.x ^ r.y ^ xi);
#else
  int a = xi, b = xi;
  asm("v_permlane32_swap_b32 %0, %1" : "+v"(a), "+v"(b));
  return __builtin_bit_cast(float, a ^ b ^ xi);
#endif
}

// xor-1 neighbor exchange via DPP quad_perm [1,0,3,2]
__device__ __forceinline__ float xor1_dpp(float x) {
  int xi = __builtin_bit_cast(int, x);
  int r = __builtin_amdgcn_update_dpp(xi, xi, 0xB1, 0xF, 0xF, true);
  return __builtin_bit_cast(float, r);
}

// ---------------- Phase 1: xg GEMM (unchanged, proven) ----------------
__global__ __launch_bounds__(256) void xg_gemm(const float* __restrict__ x,
                                               const float* __restrict__ W,
                                               const float* __restrict__ bih,
                                               const float* __restrict__ bhh,
                                               float* __restrict__ outp) {
  __shared__ float xs[16][68];
  __shared__ float ws[16][128];
  const int tid = threadIdx.x;
  const int m0 = blockIdx.x * 64;
  const int tr = tid >> 5;
  const int tc = tid & 31;
  const int tm = tr * 8;
  const int tn = tc * 4;
  const int sxm = tid >> 2;
  const int sxk = (tid & 3) * 4;
  const int swg = tid >> 1;
  const int swk = (tid & 1) * 8;

  float acc[8][4];
#pragma unroll
  for (int i = 0; i < 8; ++i)
#pragma unroll
    for (int j = 0; j < 4; ++j) acc[i][j] = 0.f;

  for (int k0 = 0; k0 < DD; k0 += 16) {
    const float4 xv = *(const float4*)(x + (size_t)(m0 + sxm) * DD + k0 + sxk);
    xs[sxk + 0][sxm] = xv.x;
    xs[sxk + 1][sxm] = xv.y;
    xs[sxk + 2][sxm] = xv.z;
    xs[sxk + 3][sxm] = xv.w;
    const float4 wv0 = *(const float4*)(W + (size_t)swg * DD + k0 + swk);
    const float4 wv1 = *(const float4*)(W + (size_t)swg * DD + k0 + swk + 4);
    ws[swk + 0][swg] = wv0.x;
    ws[swk + 1][swg] = wv0.y;
    ws[swk + 2][swg] = wv0.z;
    ws[swk + 3][swg] = wv0.w;
    ws[swk + 4][swg] = wv1.x;
    ws[swk + 5][swg] = wv1.y;
    ws[swk + 6][swg] = wv1.z;
    ws[swk + 7][swg] = wv1.w;
    __syncthreads();
#pragma unroll
    for (int k = 0; k < 16; ++k) {
      const float4 a0 = *(const float4*)&xs[k][tm];
      const float4 a1 = *(const float4*)&xs[k][tm + 4];
      const float4 wv = *(const float4*)&ws[k][tn];
      const float xr[8] = {a0.x, a0.y, a0.z, a0.w, a1.x, a1.y, a1.z, a1.w};
      const float wr[4] = {wv.x, wv.y, wv.z, wv.w};
#pragma unroll
      for (int i = 0; i < 8; ++i)
#pragma unroll
        for (int j = 0; j < 4; ++j) acc[i][j] = fmaf(xr[i], wr[j], acc[i][j]);
    }
    __syncthreads();
  }
  const float4 bi = *(const float4*)(bih + tn);
  const float4 bh = *(const float4*)(bhh + tn);
  const float bs[4] = {bi.x + bh.x, bi.y + bh.y, bi.z + bh.z, bi.w + bh.w};
#pragma unroll
  for (int i = 0; i < 8; ++i) {
    float4 o;
    o.x = acc[i][0] + bs[0];
    o.y = acc[i][1] + bs[1];
    o.z = acc[i][2] + bs[2];
    o.w = acc[i][3] + bs[3];
    *(float4*)(outp + (size_t)(m0 + tm + i) * GG + tn) = o;
  }
}

// ---------------- Phase 2: single-wave-per-batch scan (R6 + pinned weights) -
__global__ __launch_bounds__(64)
__attribute__((amdgpu_waves_per_eu(1)))
void lstm_scan(const float* __restrict__ xg,
               const float* __restrict__ Whh0,
               const float* __restrict__ Wih1,
               const float* __restrict__ Whh1,
               const float* __restrict__ bih1,
               const float* __restrict__ bhh1,
               float* __restrict__ out) {
  const int l = threadIdx.x;
  const int j = l & 31;
  const int hi = l >> 5;
  const int b = blockIdx.x;
  const int gA = j + 64 * hi;
  const int gB = gA + 32;

  uint32_t w0A[16], w0B[16], wiA[16], whA[16], wiB[16], whB[16];
#pragma unroll
  for (int q = 0; q < 8; ++q) {
    float4 a = *(const float4*)(Whh0 + (size_t)gA * HH + q * 4);
    float4 c = *(const float4*)(Whh0 + (size_t)gB * HH + q * 4);
    w0A[2 * q] = pack2(a.x, a.y); w0A[2 * q + 1] = pack2(a.z, a.w);
    w0B[2 * q] = pack2(c.x, c.y); w0B[2 * q + 1] = pack2(c.z, c.w);
    float4 d = *(const float4*)(Wih1 + (size_t)gA * HH + q * 4);
    float4 e = *(const float4*)(Wih1 + (size_t)gB * HH + q * 4);
    wiA[2 * q] = pack2(d.x, d.y); wiA[2 * q + 1] = pack2(d.z, d.w);
    wiB[2 * q] = pack2(e.x, e.y); wiB[2 * q + 1] = pack2(e.z, e.w);
    float4 f = *(const float4*)(Whh1 + (size_t)gA * HH + q * 4);
    float4 g = *(const float4*)(Whh1 + (size_t)gB * HH + q * 4);
    whA[2 * q] = pack2(f.x, f.y); whA[2 * q + 1] = pack2(f.z, f.w);
    whB[2 * q] = pack2(g.x, g.y); whB[2 * q + 1] = pack2(g.z, g.w);
  }
  // Pin all 96 weight dwords: opaque defs -> cannot be rematerialized from
  // memory; with waves_per_eu(1) budget they stay VGPR-resident.
#pragma unroll
  for (int k = 0; k < 16; ++k) {
    asm volatile("" : "+v"(w0A[k]));
    asm volatile("" : "+v"(w0B[k]));
    asm volatile("" : "+v"(wiA[k]));
    asm volatile("" : "+v"(wiB[k]));
    asm volatile("" : "+v"(whA[k]));
    asm volatile("" : "+v"(whB[k]));
  }
  const float b1A = bih1[gA] + bhh1[gA];
  const float b1B = bih1[gB] + bhh1[gB];

  uint32_t h0p[16], h1p[16];  // wave-uniform packed-f16 h state (SGPRs)
#pragma unroll
  for (int k = 0; k < 16; ++k) { h0p[k] = 0u; h1p[k] = 0u; }
  float c0 = 0.f, c1 = 0.f;

  const float* xgp = xg + (size_t)b * TT * GG;
  float* outp = out + (size_t)b * TT * HH;

  float xA[4], xB[4];
#pragma unroll
  for (int u = 0; u < 4; ++u) {
    xA[u] = xgp[u * GG + gA];
    xB[u] = xgp[u * GG + gB];
  }

  for (int tb = 0; tb < TT; tb += 4) {
#pragma unroll
    for (int u = 0; u < 4; ++u) {
      const int t = tb + u;
      float sA0 = xA[u], sB0 = xB[u];
      const int tp = (t + 4 < TT) ? (t + 4) : (TT - 1);
      xA[u] = xgp[(size_t)tp * GG + gA];
      xB[u] = xgp[(size_t)tp * GG + gB];
      // ---- layer0 dots (h0p = h0[t-1]) ----
      float pA = 0.f, pB = 0.f;
#pragma unroll
      for (int k = 0; k < 16; k += 2) {
        sA0 = dot2(w0A[k], h0p[k], sA0);
        pA  = dot2(w0A[k + 1], h0p[k + 1], pA);
        sB0 = dot2(w0B[k], h0p[k], sB0);
        pB  = dot2(w0B[k + 1], h0p[k + 1], pB);
      }
      sA0 += pA; sB0 += pB;
      // ---- layer1 dots for step t-1 (h0p=h0[t-1], h1p=h1[t-2]) ----
      float sA1 = b1A, sB1 = b1B, qA = 0.f, qB = 0.f;
#pragma unroll
      for (int k = 0; k < 16; k += 2) {
        sA1 = dot2(wiA[k], h0p[k], sA1);
        qA  = dot2(wiA[k + 1], h0p[k + 1], qA);
        sB1 = dot2(wiB[k], h0p[k], sB1);
        qB  = dot2(wiB[k + 1], h0p[k + 1], qB);
        sA1 = dot2(whA[k], h1p[k], sA1);
        qA  = dot2(whA[k + 1], h1p[k + 1], qA);
        sB1 = dot2(whB[k], h1p[k], sB1);
        qB  = dot2(whB[k + 1], h1p[k + 1], qB);
      }
      sA1 += qA; sB1 += qB;
      // ---- layer0 combine -> h0[t] ----
      {
        float aA = act_sel(sA0, hi != 0);  // i (hi=0) / g (hi=1)
        float aB = sigm(sB0);              // f (hi=0) / o (hi=1)
        float pAx = partner32(aA);
        float pBx = partner32(aB);
        float gi = hi ? pAx : aA;
        float gf = hi ? pBx : aB;
        float gg = hi ? aA : pAx;
        float go = hi ? aB : pBx;
        c0 = fmaf(gf, c0, gi * gg);
        float h = go * fast_tanh(c0);
        float oth = xor1_dpp(h);
        float lo = (j & 1) ? oth : h;
        float hh = (j & 1) ? h : oth;
        uint32_t pk = pack2(lo, hh);
#pragma unroll
        for (int m = 0; m < 16; ++m)
          h0p[m] = (uint32_t)__builtin_amdgcn_readlane((int)pk, 2 * m);
      }
      // ---- layer1 combine for step t-1 ----
      if (t > 0) {
        float aA = act_sel(sA1, hi != 0);
        float aB = sigm(sB1);
        float pAx = partner32(aA);
        float pBx = partner32(aB);
        float gi = hi ? pAx : aA;
        float gf = hi ? pBx : aB;
        float gg = hi ? aA : pAx;
        float go = hi ? aB : pBx;
        c1 = fmaf(gf, c1, gi * gg);
        float h = go * fast_tanh(c1);
        if (!hi) outp[(size_t)(t - 1) * HH + j] = h;
        float oth = xor1_dpp(h);
        float lo = (j & 1) ? oth : h;
        float hh = (j & 1) ? h : oth;
        uint32_t pk = pack2(lo, hh);
#pragma unroll
        for (int m = 0; m < 16; ++m)
          h1p[m] = (uint32_t)__builtin_amdgcn_readlane((int)pk, 2 * m);
      }
    }
  }
  // ---- final layer1 step (t = TT-1): h0p=h0[TT-1], h1p=h1[TT-2] ----
  {
    float sA1 = b1A, sB1 = b1B, qA = 0.f, qB = 0.f;
#pragma unroll
    for (int k = 0; k < 16; k += 2) {
      sA1 = dot2(wiA[k], h0p[k], sA1);
      qA  = dot2(wiA[k + 1], h0p[k + 1], qA);
      sB1 = dot2(wiB[k], h0p[k], sB1);
      qB  = dot2(wiB[k + 1], h0p[k + 1], qB);
      sA1 = dot2(whA[k], h1p[k], sA1);
      qA  = dot2(whA[k + 1], h1p[k + 1], qA);
      sB1 = dot2(whB[k], h1p[k], sB1);
      qB  = dot2(whB[k + 1], h1p[k + 1], qB);
    }
    sA1 += qA; sB1 += qB;
    float aA = act_sel(sA1, hi != 0);
    float aB = sigm(sB1);
    float pAx = partner32(aA);
    float pBx = partner32(aB);
    float gi = hi ? pAx : aA;
    float gf = hi ? pBx : aB;
    float gg = hi ? aA : pAx;
    float go = hi ? aB : pBx;
    c1 = fmaf(gf, c1, gi * gg);
    float h = go * fast_tanh(c1);
    if (!hi) outp[(size_t)(TT - 1) * HH + j] = h;
  }
}

extern "C" void kernel_launch(void* const* d_in, const int* in_sizes, int n_in,
                              void* d_out, int out_size, void* d_ws, size_t ws_size,
                              hipStream_t stream) {
  const float* x = (const float*)d_in[0];
  const float* Wih0 = (const float*)d_in[1];
  const float* Whh0 = (const float*)d_in[2];
  const float* bih0 = (const float*)d_in[3];
  const float* bhh0 = (const float*)d_in[4];
  const float* Wih1 = (const float*)d_in[5];
  const float* Whh1 = (const float*)d_in[6];
  const float* bih1 = (const float*)d_in[7];
  const float* bhh1 = (const float*)d_in[8];
  float* out = (float*)d_out;
  float* xg = (float*)d_ws;  // B*T*4H*4 = 33.5 MB scratch

  xg_gemm<<<dim3((BB * TT) / 64), dim3(256), 0, stream>>>(x, Wih0, bih0, bhh0, xg);
  lstm_scan<<<dim3(BB), dim3(64), 0, stream>>>(xg, Whh0, Wih1, Whh1, bih1, bhh1, out);
}

// Round 14
// 497.157 us; speedup vs baseline: 1.9127x; 1.1540x over previous
//
#include <hip/hip_runtime.h>
#include <stdint.h>

// 2-layer LSTM, B=64, T=1024, D=512, H=32, fp32 in/out.
// Phase 1: xg0 = x @ Wih0^T + b0 -- f16 MFMA GEMM (v_mfma_f32_16x16x32_f16),
//   f32->f16 conversion during LDS staging, f32 accumulate. M=65536,N=128,K=512.
// Phase 2: fused 2-layer scan (R6/R13 structure, measured floor ~464us).

#define TT 1024
#define BB 64
#define DD 512
#define HH 32
#define GG 128  // 4*H

typedef _Float16 h2v __attribute__((ext_vector_type(2)));
typedef __fp16 pk2 __attribute__((ext_vector_type(2)));
typedef int int2v __attribute__((ext_vector_type(2)));
typedef _Float16 f16x8 __attribute__((ext_vector_type(8)));
typedef float f32x4 __attribute__((ext_vector_type(4)));

__device__ __forceinline__ uint32_t pack2(float lo, float hi) {
  pk2 p = __builtin_amdgcn_cvt_pkrtz(lo, hi);
  return __builtin_bit_cast(uint32_t, p);
}
__device__ __forceinline__ float dot2(uint32_t a, uint32_t b, float acc) {
  return __builtin_amdgcn_fdot2(__builtin_bit_cast(h2v, a),
                                __builtin_bit_cast(h2v, b), acc, false);
}
__device__ __forceinline__ float fast_rcp(float x) { return __builtin_amdgcn_rcpf(x); }
__device__ __forceinline__ float sigm(float s) { return fast_rcp(1.f + __expf(-s)); }
__device__ __forceinline__ float fast_tanh(float x) {
  return fmaf(2.f, fast_rcp(1.f + __expf(-2.f * x)), -1.f);
}
__device__ __forceinline__ float act_sel(float s, bool ist) {
  float z = ist ? s + s : s;
  float r = fast_rcp(1.f + __expf(-z));
  return ist ? fmaf(2.f, r, -1.f) : r;
}

// xor-32 partner, pure VALU; order-proof XOR extraction (verified R6).
__device__ __forceinline__ float partner32(float x) {
  int xi = __builtin_bit_cast(int, x);
#if __has_builtin(__builtin_amdgcn_permlane32_swap)
  int2v r = __builtin_amdgcn_permlane32_swap(xi, xi, false, false);
  return __builtin_bit_cast(float, r.x ^ r.y ^ xi);
#else
  int a = xi, b = xi;
  asm("v_permlane32_swap_b32 %0, %1" : "+v"(a), "+v"(b));
  return __builtin_bit_cast(float, a ^ b ^ xi);
#endif
}

// xor-1 neighbor exchange via DPP quad_perm [1,0,3,2]
__device__ __forceinline__ float xor1_dpp(float x) {
  int xi = __builtin_bit_cast(int, x);
  int r = __builtin_amdgcn_update_dpp(xi, xi, 0xB1, 0xF, 0xF, true);
  return __builtin_bit_cast(float, r);
}

// ---------------- Phase 1: f16 MFMA GEMM ----------------
// Block: 128 M-rows x 128 N (all gates). 4 waves, each 64x64 wave-tile
// (4x4 subtiles of 16x16, K-step 32 -> one mfma per subtile per step).
// Frag layout (gfx950 16x16x32 f16): A: row=lane&15, k=(lane>>4)*8..+7;
// B: col=lane&15, k=(lane>>4)*8..+7; C/D: col=lane&15, row=(lane>>4)*4+reg
// (C/D verified learn_hip m89).
__global__ __launch_bounds__(256) void xg_gemm_mfma(const float* __restrict__ x,
                                                    const float* __restrict__ W,
                                                    const float* __restrict__ bih,
                                                    const float* __restrict__ bhh,
                                                    float* __restrict__ outp) {
  __shared__ _Float16 lxs[128][40];  // [m][k], 80B row stride (16B aligned)
  __shared__ _Float16 lws[128][40];  // [g][k]
  const int tid = threadIdx.x;
  const int m0 = blockIdx.x * 128;
  // staging: thread t -> row t>>1, k-half (t&1)*16, 4x float4
  const int sr = tid >> 1;
  const int sk = (tid & 1) * 16;
  // wave tiling
  const int w = tid >> 6;
  const int wm = (w >> 1) * 64;
  const int wn = (w & 1) * 64;
  const int lane = tid & 63;
  const int lr = lane & 15;
  const int lk = (lane >> 4) * 8;

  f32x4 acc[4][4];
#pragma unroll
  for (int i = 0; i < 4; ++i)
#pragma unroll
    for (int j = 0; j < 4; ++j) acc[i][j] = (f32x4){0.f, 0.f, 0.f, 0.f};

  for (int k0 = 0; k0 < DD; k0 += 32) {
#pragma unroll
    for (int c = 0; c < 4; ++c) {
      const float4 xv = *(const float4*)(x + (size_t)(m0 + sr) * DD + k0 + sk + c * 4);
      uint2 px;
      px.x = pack2(xv.x, xv.y);
      px.y = pack2(xv.z, xv.w);
      *(uint2*)&lxs[sr][sk + c * 4] = px;
      const float4 wv = *(const float4*)(W + (size_t)sr * DD + k0 + sk + c * 4);
      uint2 pw;
      pw.x = pack2(wv.x, wv.y);
      pw.y = pack2(wv.z, wv.w);
      *(uint2*)&lws[sr][sk + c * 4] = pw;
    }
    __syncthreads();
    f16x8 af[4], bf[4];
#pragma unroll
    for (int s = 0; s < 4; ++s) {
      af[s] = *(const f16x8*)&lxs[wm + s * 16 + lr][lk];
      bf[s] = *(const f16x8*)&lws[wn + s * 16 + lr][lk];
    }
#pragma unroll
    for (int mi = 0; mi < 4; ++mi)
#pragma unroll
      for (int ni = 0; ni < 4; ++ni)
        acc[mi][ni] = __builtin_amdgcn_mfma_f32_16x16x32_f16(af[mi], bf[ni],
                                                             acc[mi][ni], 0, 0, 0);
    __syncthreads();
  }
  // epilogue: add bias, store f32
  const int rq = (lane >> 4) * 4;
#pragma unroll
  for (int ni = 0; ni < 4; ++ni) {
    const int g = wn + ni * 16 + lr;
    const float bsum = bih[g] + bhh[g];
#pragma unroll
    for (int mi = 0; mi < 4; ++mi) {
      const int mbase = m0 + wm + mi * 16 + rq;
#pragma unroll
      for (int q = 0; q < 4; ++q)
        outp[(size_t)(mbase + q) * GG + g] = acc[mi][ni][q] + bsum;
    }
  }
}

// ---------------- Phase 2: single-wave-per-batch scan (R13, unchanged) ------
__global__ __launch_bounds__(64)
__attribute__((amdgpu_waves_per_eu(1)))
void lstm_scan(const float* __restrict__ xg,
               const float* __restrict__ Whh0,
               const float* __restrict__ Wih1,
               const float* __restrict__ Whh1,
               const float* __restrict__ bih1,
               const float* __restrict__ bhh1,
               float* __restrict__ out) {
  const int l = threadIdx.x;
  const int j = l & 31;
  const int hi = l >> 5;
  const int b = blockIdx.x;
  const int gA = j + 64 * hi;
  const int gB = gA + 32;

  uint32_t w0A[16], w0B[16], wiA[16], whA[16], wiB[16], whB[16];
#pragma unroll
  for (int q = 0; q < 8; ++q) {
    float4 a = *(const float4*)(Whh0 + (size_t)gA * HH + q * 4);
    float4 c = *(const float4*)(Whh0 + (size_t)gB * HH + q * 4);
    w0A[2 * q] = pack2(a.x, a.y); w0A[2 * q + 1] = pack2(a.z, a.w);
    w0B[2 * q] = pack2(c.x, c.y); w0B[2 * q + 1] = pack2(c.z, c.w);
    float4 d = *(const float4*)(Wih1 + (size_t)gA * HH + q * 4);
    float4 e = *(const float4*)(Wih1 + (size_t)gB * HH + q * 4);
    wiA[2 * q] = pack2(d.x, d.y); wiA[2 * q + 1] = pack2(d.z, d.w);
    wiB[2 * q] = pack2(e.x, e.y); wiB[2 * q + 1] = pack2(e.z, e.w);
    float4 f = *(const float4*)(Whh1 + (size_t)gA * HH + q * 4);
    float4 g = *(const float4*)(Whh1 + (size_t)gB * HH + q * 4);
    whA[2 * q] = pack2(f.x, f.y); whA[2 * q + 1] = pack2(f.z, f.w);
    whB[2 * q] = pack2(g.x, g.y); whB[2 * q + 1] = pack2(g.z, g.w);
  }
#pragma unroll
  for (int k = 0; k < 16; ++k) {
    asm volatile("" : "+v"(w0A[k]));
    asm volatile("" : "+v"(w0B[k]));
    asm volatile("" : "+v"(wiA[k]));
    asm volatile("" : "+v"(wiB[k]));
    asm volatile("" : "+v"(whA[k]));
    asm volatile("" : "+v"(whB[k]));
  }
  const float b1A = bih1[gA] + bhh1[gA];
  const float b1B = bih1[gB] + bhh1[gB];

  uint32_t h0p[16], h1p[16];
#pragma unroll
  for (int k = 0; k < 16; ++k) { h0p[k] = 0u; h1p[k] = 0u; }
  float c0 = 0.f, c1 = 0.f;

  const float* xgp = xg + (size_t)b * TT * GG;
  float* outp = out + (size_t)b * TT * HH;

  float xA[4], xB[4];
#pragma unroll
  for (int u = 0; u < 4; ++u) {
    xA[u] = xgp[u * GG + gA];
    xB[u] = xgp[u * GG + gB];
  }

  for (int tb = 0; tb < TT; tb += 4) {
#pragma unroll
    for (int u = 0; u < 4; ++u) {
      const int t = tb + u;
      float sA0 = xA[u], sB0 = xB[u];
      const int tp = (t + 4 < TT) ? (t + 4) : (TT - 1);
      xA[u] = xgp[(size_t)tp * GG + gA];
      xB[u] = xgp[(size_t)tp * GG + gB];
      float pA = 0.f, pB = 0.f;
#pragma unroll
      for (int k = 0; k < 16; k += 2) {
        sA0 = dot2(w0A[k], h0p[k], sA0);
        pA  = dot2(w0A[k + 1], h0p[k + 1], pA);
        sB0 = dot2(w0B[k], h0p[k], sB0);
        pB  = dot2(w0B[k + 1], h0p[k + 1], pB);
      }
      sA0 += pA; sB0 += pB;
      float sA1 = b1A, sB1 = b1B, qA = 0.f, qB = 0.f;
#pragma unroll
      for (int k = 0; k < 16; k += 2) {
        sA1 = dot2(wiA[k], h0p[k], sA1);
        qA  = dot2(wiA[k + 1], h0p[k + 1], qA);
        sB1 = dot2(wiB[k], h0p[k], sB1);
        qB  = dot2(wiB[k + 1], h0p[k + 1], qB);
        sA1 = dot2(whA[k], h1p[k], sA1);
        qA  = dot2(whA[k + 1], h1p[k + 1], qA);
        sB1 = dot2(whB[k], h1p[k], sB1);
        qB  = dot2(whB[k + 1], h1p[k + 1], qB);
      }
      sA1 += qA; sB1 += qB;
      {
        float aA = act_sel(sA0, hi != 0);
        float aB = sigm(sB0);
        float pAx = partner32(aA);
        float pBx = partner32(aB);
        float gi = hi ? pAx : aA;
        float gf = hi ? pBx : aB;
        float gg = hi ? aA : pAx;
        float go = hi ? aB : pBx;
        c0 = fmaf(gf, c0, gi * gg);
        float h = go * fast_tanh(c0);
        float oth = xor1_dpp(h);
        float lo = (j & 1) ? oth : h;
        float hh = (j & 1) ? h : oth;
        uint32_t pk = pack2(lo, hh);
#pragma unroll
        for (int m = 0; m < 16; ++m)
          h0p[m] = (uint32_t)__builtin_amdgcn_readlane((int)pk, 2 * m);
      }
      if (t > 0) {
        float aA = act_sel(sA1, hi != 0);
        float aB = sigm(sB1);
        float pAx = partner32(aA);
        float pBx = partner32(aB);
        float gi = hi ? pAx : aA;
        float gf = hi ? pBx : aB;
        float gg = hi ? aA : pAx;
        float go = hi ? aB : pBx;
        c1 = fmaf(gf, c1, gi * gg);
        float h = go * fast_tanh(c1);
        if (!hi) outp[(size_t)(t - 1) * HH + j] = h;
        float oth = xor1_dpp(h);
        float lo = (j & 1) ? oth : h;
        float hh = (j & 1) ? h : oth;
        uint32_t pk = pack2(lo, hh);
#pragma unroll
        for (int m = 0; m < 16; ++m)
          h1p[m] = (uint32_t)__builtin_amdgcn_readlane((int)pk, 2 * m);
      }
    }
  }
  {
    float sA1 = b1A, sB1 = b1B, qA = 0.f, qB = 0.f;
#pragma unroll
    for (int k = 0; k < 16; k += 2) {
      sA1 = dot2(wiA[k], h0p[k], sA1);
      qA  = dot2(wiA[k + 1], h0p[k + 1], qA);
      sB1 = dot2(wiB[k], h0p[k], sB1);
      qB  = dot2(wiB[k + 1], h0p[k + 1], qB);
      sA1 = dot2(whA[k], h1p[k], sA1);
      qA  = dot2(whA[k + 1], h1p[k + 1], qA);
      sB1 = dot2(whB[k], h1p[k], sB1);
      qB  = dot2(whB[k + 1], h1p[k + 1], qB);
    }
    sA1 += qA; sB1 += qB;
    float aA = act_sel(sA1, hi != 0);
    float aB = sigm(sB1);
    float pAx = partner32(aA);
    float pBx = partner32(aB);
    float gi = hi ? pAx : aA;
    float gf = hi ? pBx : aB;
    float gg = hi ? aA : pAx;
    float go = hi ? aB : pBx;
    c1 = fmaf(gf, c1, gi * gg);
    float h = go * fast_tanh(c1);
    if (!hi) outp[(size_t)(TT - 1) * HH + j] = h;
  }
}

extern "C" void kernel_launch(void* const* d_in, const int* in_sizes, int n_in,
                              void* d_out, int out_size, void* d_ws, size_t ws_size,
                              hipStream_t stream) {
  const float* x = (const float*)d_in[0];
  const float* Wih0 = (const float*)d_in[1];
  const float* Whh0 = (const float*)d_in[2];
  const float* bih0 = (const float*)d_in[3];
  const float* bhh0 = (const float*)d_in[4];
  const float* Wih1 = (const float*)d_in[5];
  const float* Whh1 = (const float*)d_in[6];
  const float* bih1 = (const float*)d_in[7];
  const float* bhh1 = (const float*)d_in[8];
  float* out = (float*)d_out;
  float* xg = (float*)d_ws;  // B*T*4H*4 = 33.5 MB scratch

  xg_gemm_mfma<<<dim3((BB * TT) / 128), dim3(256), 0, stream>>>(x, Wih0, bih0, bhh0, xg);
  lstm_scan<<<dim3(BB), dim3(64), 0, stream>>>(xg, Whh0, Wih1, Whh1, bih1, bhh1, out);
}